// Round 2
// baseline (453.310 us; speedup 1.0000x reference)
//
#include <hip/hip_runtime.h>

// ---------------------------------------------------------------------------
// PairEdgeLearnGNN on MI355X.  B=64, N=1024, D=128, KT=13, NC=2, CF=2.
//   scores = x (w1 w2^T) x^T ; adj = softmax over axis=1 (columns)
//   h = (adj + I) x ; g = h gin_w^T + gin_b ; BN1 per-n over (b,d)
//   z[b,c,d] = sum_n bn1(g) lc_w[c,n] ; conv K=13 SAME ; BN2 ; relu ; linear ; softmax
// Outputs: probs (64x2) then adj (64x1024x1024), f32, concatenated.
// ---------------------------------------------------------------------------

typedef __attribute__((ext_vector_type(8))) short bf16x8;
typedef __attribute__((ext_vector_type(4))) float f32x4;

__device__ __forceinline__ float b2f(unsigned short s){
  union { unsigned u; float f; } v; v.u = ((unsigned)s) << 16; return v.f;
}
__device__ __forceinline__ unsigned short f2b(float f){
  union { float f; unsigned u; } v; v.f = f;
  unsigned r = v.u + 0x7fffu + ((v.u >> 16) & 1u);
  return (unsigned short)(r >> 16);
}

#define MFMA16(a, b, c) __builtin_amdgcn_mfma_f32_16x16x32_bf16((a), (b), (c), 0, 0, 0)

// ---------------------------------------------------------------------------
// prep: blk<8192: 32x32 transpose tiles -> xb (bf16) + xbT (bf16)
//       blk in [8192,8256): cast gin_w -> bf16
//       blk in [8256,8320): Mt[d][k] = sum_e w1[k,e] w2[d,e]
// ---------------------------------------------------------------------------
__global__ __launch_bounds__(256) void k_prep(
    const float* __restrict__ x, const float* __restrict__ w1, const float* __restrict__ w2,
    const float* __restrict__ gin_w,
    unsigned short* __restrict__ xb, unsigned short* __restrict__ xbT,
    unsigned short* __restrict__ mt, unsigned short* __restrict__ ginb)
{
  int blk = blockIdx.x, tid = threadIdx.x;
  if (blk < 8192) {
    __shared__ float tile[32][33];
    int b = blk >> 7, t = blk & 127;
    int j0 = (t >> 2) << 5, d0 = (t & 3) << 5;
    int tx = tid & 31, ty = tid >> 5;
#pragma unroll
    for (int r0 = 0; r0 < 32; r0 += 8) {
      int r = ty + r0;
      int idx = (((b << 10) + j0 + r) << 7) + d0 + tx;
      float v = x[idx];
      tile[r][tx] = v;
      xb[idx] = f2b(v);
    }
    __syncthreads();
#pragma unroll
    for (int r0 = 0; r0 < 32; r0 += 8) {
      int r = ty + r0;
      xbT[(((b << 7) + d0 + r) << 10) + j0 + tx] = f2b(tile[tx][r]);
    }
  } else if (blk < 8256) {
    int i = ((blk - 8192) << 8) + tid;
    ginb[i] = f2b(gin_w[i]);
  } else {
    int i = ((blk - 8256) << 8) + tid;
    int d = i >> 7, k = i & 127;
    float s = 0.f;
    for (int e = 0; e < 128; ++e) s += w1[(k << 7) + e] * w2[(d << 7) + e];
    mt[(d << 7) + k] = f2b(s);
  }
}

// ---------------------------------------------------------------------------
// NT GEMM, M x 128, K=128, 16 rows/wave, 64 rows/block, grid = M/64.
// ---------------------------------------------------------------------------
__global__ __launch_bounds__(256, 4) void k_gemm_nt128(
    const unsigned short* __restrict__ A, const unsigned short* __restrict__ Bt,
    const float* __restrict__ bias, unsigned short* __restrict__ Out)
{
  int row0 = blockIdx.x << 6;
  int tid = threadIdx.x;
  int wave = tid >> 6, lane = tid & 63, lr = lane & 15, lg = lane >> 4;
  int rw = row0 + (wave << 4);
  bf16x8 af[4];
#pragma unroll
  for (int kk = 0; kk < 4; kk++)
    af[kk] = *(const bf16x8*)&A[((size_t)(rw + lr) << 7) + (kk << 5) + (lg << 3)];
  f32x4 acc[8] = {};
#pragma unroll
  for (int kk = 0; kk < 4; kk++) {
    bf16x8 bb[8];
#pragma unroll
    for (int cf = 0; cf < 8; cf++)
      bb[cf] = *(const bf16x8*)&Bt[(((cf << 4) + lr) << 7) + (kk << 5) + (lg << 3)];
#pragma unroll
    for (int cf = 0; cf < 8; cf++)
      acc[cf] = MFMA16(af[kk], bb[cf], acc[cf]);
  }
#pragma unroll
  for (int cf = 0; cf < 8; cf++) {
    int col = (cf << 4) + lr;
    float bv = bias ? bias[col] : 0.f;
    int rowb = rw + (lg << 2);
#pragma unroll
    for (int r = 0; r < 4; r++)
      Out[((size_t)(rowb + r) << 7) + col] = f2b(acc[cf][r] + bv);
  }
}

// ---------------------------------------------------------------------------
// colsum: per (b, it) 64 rows (16/wave), loop jt, barrier-free, per-wave
// deterministic partials psum[it*4+wave][b*1024+j]. XCD-swizzled.
// ---------------------------------------------------------------------------
__global__ __launch_bounds__(256, 4) void k_colsum(
    const unsigned short* __restrict__ qb, const unsigned short* __restrict__ xb,
    float* __restrict__ psum)
{
  int bid = blockIdx.x;
  int l = ((bid & 7) << 7) + (bid >> 3);      // XCD r gets b in [r*8, r*8+8)
  int b = l >> 4, it = l & 15;
  int i0 = it << 6;
  int tid = threadIdx.x, wave = tid >> 6, lane = tid & 63, lr = lane & 15, lg = lane >> 4;
  const unsigned short* Ab = qb + ((size_t)(b << 10) << 7);
  const unsigned short* Bb = xb + ((size_t)(b << 10) << 7);
  bf16x8 af[4];
#pragma unroll
  for (int kk = 0; kk < 4; kk++)
    af[kk] = *(const bf16x8*)&Ab[((size_t)(i0 + (wave << 4) + lr) << 7) + (kk << 5) + (lg << 3)];

  for (int jt = 0; jt < 8; jt++) {
    int j0 = jt << 7;
    f32x4 s[8] = {};
#pragma unroll
    for (int kk = 0; kk < 4; kk++) {
      bf16x8 bb[8];
#pragma unroll
      for (int cf = 0; cf < 8; cf++)
        bb[cf] = *(const bf16x8*)&Bb[((size_t)(j0 + (cf << 4) + lr) << 7) + (kk << 5) + (lg << 3)];
#pragma unroll
      for (int cf = 0; cf < 8; cf++)
        s[cf] = MFMA16(af[kk], bb[cf], s[cf]);
    }
    float ps[8];
#pragma unroll
    for (int cf = 0; cf < 8; cf++) {
      float p = 0.f;
#pragma unroll
      for (int r = 0; r < 4; r++) p += __expf(s[cf][r]);
      p += __shfl_xor(p, 16);
      p += __shfl_xor(p, 32);
      ps[cf] = p;
    }
    if (lane < 16) {
#pragma unroll
      for (int cf = 0; cf < 8; cf++)
        psum[(size_t)((it << 2) + wave) * 65536 + (b << 10) + j0 + (cf << 4) + lane] = ps[cf];
    }
  }
}

__global__ void k_rcol(const float* __restrict__ psum, float* __restrict__ rcol)
{
  int i = (blockIdx.x << 8) + threadIdx.x;
  float s = 0.f;
#pragma unroll
  for (int p = 0; p < 64; p++) s += psum[(size_t)p * 65536 + i];
  rcol[i] = 1.f / s;
}

// ---------------------------------------------------------------------------
// fused adj + h = (adj+I)x.  32 rows/wave, barrier-free jt loop (per-wave
// private swizzled LDS for the P transpose), A-strip hoisted, rcol preloaded,
// XCD-swizzled so each XCD keeps its 8 b's x-tiles L2-resident.
// ---------------------------------------------------------------------------
__global__ __launch_bounds__(256, 2) void k_attn(
    const unsigned short* __restrict__ qb, const unsigned short* __restrict__ xb,
    const unsigned short* __restrict__ xbT, const float* __restrict__ rcol,
    float* __restrict__ adj, unsigned short* __restrict__ hb)
{
  int bid = blockIdx.x;
  int l = ((bid & 7) << 6) + (bid >> 3);      // XCD r gets b in [r*8, r*8+8)
  int b = l >> 3, it = l & 7;
  int i0 = it << 7;
  int tid = threadIdx.x, wave = tid >> 6, lane = tid & 63, lr = lane & 15, lg = lane >> 4;
  __shared__ unsigned short plds[4][32][128];   // per-wave private, XOR-swizzled
  __shared__ float rc[1024];
  const unsigned short* Ab = qb + ((size_t)(b << 10) << 7);
  const unsigned short* Xb = xb + ((size_t)(b << 10) << 7);
  const unsigned short* Xt = xbT + ((size_t)(b << 7) << 10);

  rc[tid] = rcol[(b << 10) + tid];
  rc[tid + 256] = rcol[(b << 10) + tid + 256];
  rc[tid + 512] = rcol[(b << 10) + tid + 512];
  rc[tid + 768] = rcol[(b << 10) + tid + 768];

  bf16x8 af[4][2];
#pragma unroll
  for (int kk = 0; kk < 4; kk++)
#pragma unroll
    for (int fi = 0; fi < 2; fi++)
      af[kk][fi] = *(const bf16x8*)&Ab[((size_t)(i0 + (wave << 5) + (fi << 4) + lr) << 7) + (kk << 5) + (lg << 3)];

  __syncthreads();   // rc ready; no further block barriers

  f32x4 h[2][8] = {};
  for (int jt = 0; jt < 8; jt++) {
    int j0 = jt << 7;
    f32x4 s[2][8] = {};
#pragma unroll
    for (int kk = 0; kk < 4; kk++) {
      bf16x8 bb[8];
#pragma unroll
      for (int cf = 0; cf < 8; cf++)
        bb[cf] = *(const bf16x8*)&Xb[((size_t)(j0 + (cf << 4) + lr) << 7) + (kk << 5) + (lg << 3)];
#pragma unroll
      for (int fi = 0; fi < 2; fi++)
#pragma unroll
        for (int cf = 0; cf < 8; cf++)
          s[fi][cf] = MFMA16(af[kk][fi], bb[cf], s[fi][cf]);
    }

    // exp * rcol -> adj write (f32) + swizzled per-wave LDS (bf16)
#pragma unroll
    for (int fi = 0; fi < 2; fi++) {
#pragma unroll
      for (int cf = 0; cf < 8; cf++) {
        int colj = (cf << 4) + lr;
        float rv = rc[j0 + colj];
#pragma unroll
        for (int r = 0; r < 4; r++) {
          int lrow = (fi << 4) + (lg << 2) + r;
          float p = __expf(s[fi][cf][r]) * rv;
          int irow = i0 + (wave << 5) + lrow;
          adj[((size_t)((b << 10) + irow) << 10) + j0 + colj] = p;
          int sw = (colj >> 3) ^ (lrow & 7);
          plds[wave][lrow][(sw << 3) | (colj & 7)] = f2b(p);
        }
      }
    }
    // no barrier: plds slice is wave-private (compiler lgkmcnt orders it)

    // PV: h += P @ x
#pragma unroll
    for (int kk = 0; kk < 4; kk++) {
      bf16x8 pa[2], vb[8];
#pragma unroll
      for (int fi = 0; fi < 2; fi++) {
        int lrow = (fi << 4) + lr;
        int jb = ((kk << 2) + lg) ^ (lrow & 7);
        pa[fi] = *(const bf16x8*)&plds[wave][lrow][jb << 3];
      }
#pragma unroll
      for (int cf = 0; cf < 8; cf++)
        vb[cf] = *(const bf16x8*)&Xt[((size_t)((cf << 4) + lr) << 10) + j0 + (kk << 5) + (lg << 3)];
#pragma unroll
      for (int fi = 0; fi < 2; fi++)
#pragma unroll
        for (int cf = 0; cf < 8; cf++)
          h[fi][cf] = MFMA16(pa[fi], vb[cf], h[fi][cf]);
    }
  }

  // epilogue: h += x ; store bf16
#pragma unroll
  for (int fi = 0; fi < 2; fi++) {
#pragma unroll
    for (int cf = 0; cf < 8; cf++) {
      int col = (cf << 4) + lr;
      int rowb = i0 + (wave << 5) + (fi << 4) + (lg << 2);
#pragma unroll
      for (int r = 0; r < 4; r++) {
        int row = rowb + r;
        float v = h[fi][cf][r] + b2f(Xb[((size_t)row << 7) + col]);
        hb[((size_t)((b << 10) + row) << 7) + col] = f2b(v);
      }
    }
  }
}

// ---------------------------------------------------------------------------
// BN1 stats per n over (b,d) -> folded lc weights
// ---------------------------------------------------------------------------
__global__ __launch_bounds__(256) void k_bnstats(
    const unsigned short* __restrict__ gb, const float* __restrict__ lc_w,
    const float* __restrict__ lc_b, const float* __restrict__ bn1_g,
    const float* __restrict__ bn1_b, float* __restrict__ wprime, float* __restrict__ bterm)
{
  int n = blockIdx.x, tid = threadIdx.x;
  float s = 0.f, s2 = 0.f;
  for (int i = tid; i < 8192; i += 256) {
    int b = i >> 7, d = i & 127;
    float v = b2f(gb[((size_t)((b << 10) + n) << 7) + d]);
    s += v; s2 += v * v;
  }
  __shared__ float rs[256], rs2[256];
  rs[tid] = s; rs2[tid] = s2;
  __syncthreads();
  for (int o = 128; o > 0; o >>= 1) {
    if (tid < o) { rs[tid] += rs[tid + o]; rs2[tid] += rs2[tid + o]; }
    __syncthreads();
  }
  if (tid == 0) {
    float m = rs[0] * (1.f / 8192.f);
    float var = rs2[0] * (1.f / 8192.f) - m * m;
    float r = rsqrtf(var + 1e-5f);
    float rg = r * bn1_g[n];
    float t = bn1_b[n] - m * rg;
#pragma unroll
    for (int c = 0; c < 2; c++) {
      float w = lc_w[(c << 10) + n];
      wprime[(c << 10) + n] = w * rg;
      float bt = w * t;
      if (n == 0) bt += lc_b[c];
      bterm[(c << 10) + n] = bt;
    }
  }
}

__global__ __launch_bounds__(128) void k_zred(
    const unsigned short* __restrict__ gb, const float* __restrict__ wprime,
    float* __restrict__ zp)
{
  int blk = blockIdx.x;
  int b = blk >> 3, nc = blk & 7, n0 = nc << 7, d = threadIdx.x;
  float a0 = 0.f, a1 = 0.f;
  for (int n = n0; n < n0 + 128; ++n) {
    float w0 = wprime[n], w1v = wprime[1024 + n];
    float g = b2f(gb[((size_t)((b << 10) + n) << 7) + d]);
    a0 += g * w0; a1 += g * w1v;
  }
  zp[(size_t)nc * 16384 + ((b << 1) << 7) + d] = a0;
  zp[(size_t)nc * 16384 + (((b << 1) | 1) << 7) + d] = a1;
}

__global__ __launch_bounds__(1024) void k_final(
    const float* __restrict__ zp, const float* __restrict__ bterm,
    const float* __restrict__ conv_w, const float* __restrict__ conv_b,
    const float* __restrict__ bn2_g, const float* __restrict__ bn2_b,
    const float* __restrict__ out_w, const float* __restrict__ out_b,
    float* __restrict__ probs)
{
  __shared__ float smem[16384];
  __shared__ float bp[2], ms[2];
  __shared__ float cw[26];
  int tid = threadIdx.x;
  if (tid < 26) cw[tid] = conv_w[tid];

  for (int c = 0; c < 2; c++) {
    smem[tid] = bterm[(c << 10) + tid];
    __syncthreads();
    for (int o = 512; o > 0; o >>= 1) {
      if (tid < o) smem[tid] += smem[tid + o];
      __syncthreads();
    }
    if (tid == 0) bp[c] = smem[0];
    __syncthreads();
  }

  for (int i = tid; i < 16384; i += 1024) {
    float s = 0.f;
#pragma unroll
    for (int p = 0; p < 8; p++) s += zp[(size_t)p * 16384 + i];
    smem[i] = s + bp[(i >> 7) & 1];
  }
  __syncthreads();

  float o[8];
  float s = 0.f, s2 = 0.f;
#pragma unroll
  for (int k = 0; k < 8; k++) {
    int i = tid + (k << 10);
    int b = i >> 7, d = i & 127;
    float acc = conv_b[0];
#pragma unroll
    for (int c = 0; c < 2; c++) {
      const float* zrow = &smem[((b << 1) | c) << 7];
#pragma unroll
      for (int t = 0; t < 13; t++) {
        int dd = d + t - 6;
        if (dd >= 0 && dd < 128) acc += zrow[dd] * cw[c * 13 + t];
      }
    }
    o[k] = acc; s += acc; s2 += acc * acc;
  }
  __syncthreads();
  smem[tid] = s; smem[1024 + tid] = s2;
  __syncthreads();
  for (int off = 512; off > 0; off >>= 1) {
    if (tid < off) { smem[tid] += smem[tid + off]; smem[1024 + tid] += smem[1024 + tid + off]; }
    __syncthreads();
  }
  if (tid == 0) {
    float m = smem[0] * (1.f / 8192.f);
    float var = smem[1024] * (1.f / 8192.f) - m * m;
    ms[0] = m; ms[1] = rsqrtf(var + 1e-5f);
  }
  __syncthreads();
  float m = ms[0], r = ms[1], g2 = bn2_g[0], b2v = bn2_b[0];
#pragma unroll
  for (int k = 0; k < 8; k++) {
    int i = tid + (k << 10);
    smem[i & 8191] = fmaxf(0.f, (o[k] - m) * r * g2 + b2v);
  }
  __syncthreads();

  int b = tid >> 4, q = tid & 15;
  float l0 = 0.f, l1 = 0.f;
#pragma unroll
  for (int k = 0; k < 8; k++) {
    int d = q + (k << 4);
    float uv = smem[(b << 7) + d];
    l0 += uv * out_w[d];
    l1 += uv * out_w[128 + d];
  }
#pragma unroll
  for (int off = 8; off > 0; off >>= 1) { l0 += __shfl_xor(l0, off); l1 += __shfl_xor(l1, off); }
  if (q == 0) {
    l0 += out_b[0]; l1 += out_b[1];
    float mm = fmaxf(l0, l1);
    float e0 = __expf(l0 - mm), e1 = __expf(l1 - mm);
    float inv = 1.f / (e0 + e1);
    probs[(b << 1)] = e0 * inv;
    probs[(b << 1) | 1] = e1 * inv;
  }
}

// ---------------------------------------------------------------------------
extern "C" void kernel_launch(void* const* d_in, const int* in_sizes, int n_in,
                              void* d_out, int out_size, void* d_ws, size_t ws_size,
                              hipStream_t stream)
{
  const float* x      = (const float*)d_in[0];
  const float* w1     = (const float*)d_in[1];
  const float* w2     = (const float*)d_in[2];
  const float* gin_w  = (const float*)d_in[3];
  const float* gin_b  = (const float*)d_in[4];
  const float* bn1_g  = (const float*)d_in[5];
  const float* bn1_b  = (const float*)d_in[6];
  const float* lc_w   = (const float*)d_in[7];
  const float* lc_b   = (const float*)d_in[8];
  const float* conv_w = (const float*)d_in[9];
  const float* conv_b = (const float*)d_in[10];
  const float* bn2_g  = (const float*)d_in[11];
  const float* bn2_b  = (const float*)d_in[12];
  const float* out_w  = (const float*)d_in[13];
  const float* out_b  = (const float*)d_in[14];

  char* ws = (char*)d_ws;
  unsigned short* xb   = (unsigned short*)(ws);                       // 16 MiB
  unsigned short* xbT  = (unsigned short*)(ws + ((size_t)16 << 20));  // 16 MiB
  unsigned short* qb   = (unsigned short*)(ws + ((size_t)32 << 20));  // 16 MiB
  unsigned short* hb   = (unsigned short*)(ws + ((size_t)48 << 20));  // 16 MiB
  float* psum = (float*)hb;            // alias: psum dead before hb written
  unsigned short* mt   = (unsigned short*)(ws + ((size_t)64 << 20));            // 32 KiB
  unsigned short* ginb = (unsigned short*)(ws + ((size_t)64 << 20) + (32u << 10));
  float* rcolp  = (float*)(ws + ((size_t)64 << 20) + (64u << 10));              // 256 KiB
  float* wprime = (float*)(ws + ((size_t)64 << 20) + (320u << 10));
  float* bterm  = (float*)(ws + ((size_t)64 << 20) + (328u << 10));
  float* zp     = (float*)(ws + ((size_t)64 << 20) + (336u << 10));             // 512 KiB
  unsigned short* gb = xb;             // alias: xb dead after k_attn

  float* probs = (float*)d_out;
  float* adj   = probs + 128;

  k_prep<<<8320, 256, 0, stream>>>(x, w1, w2, gin_w, xb, xbT, mt, ginb);
  k_gemm_nt128<<<1024, 256, 0, stream>>>(xb, mt, nullptr, qb);        // q = x (w1 w2^T)
  k_colsum<<<1024, 256, 0, stream>>>(qb, xb, psum);
  k_rcol<<<256, 256, 0, stream>>>(psum, rcolp);
  k_attn<<<512, 256, 0, stream>>>(qb, xb, xbT, rcolp, adj, hb);       // adj + h=(adj+I)x
  k_gemm_nt128<<<1024, 256, 0, stream>>>(hb, ginb, gin_b, gb);        // g = h gin_w^T + b
  k_bnstats<<<1024, 256, 0, stream>>>(gb, lc_w, lc_b, bn1_g, bn1_b, wprime, bterm);
  k_zred<<<512, 128, 0, stream>>>(gb, wprime, zp);
  k_final<<<1, 1024, 0, stream>>>(zp, bterm, conv_w, conv_b, bn2_g, bn2_b, out_w, out_b, probs);
}